// Round 2
// baseline (1221.117 us; speedup 1.0000x reference)
//
#include <hip/hip_runtime.h>
#include <hip/hip_bf16.h>
#include <math.h>

// TransformerEncoder (Shaw relative attention), MI355X gfx950.
// All GEMMs: C = A @ B^T, A[M,K], B[N,K] row-major, bf16 MFMA 16x16x32, fp32 acc.
// R = pos + typ folded once; V and R also stored transposed so every GEMM is B^T-form.
// Workspace: 312 MB via lifetime-aliased bump allocator; static-constructor hipMalloc
// fallback if the harness workspace is smaller than that.

typedef __hip_bfloat16 bf16;
typedef short short8 __attribute__((ext_vector_type(8)));
typedef float f32x4 __attribute__((ext_vector_type(4)));

constexpr int Lc = 512;      // sequence length (also S)
constexpr int Bc = 8;        // batch
constexpr int Ec = 1024;     // embed
constexpr int Hc = 16;       // heads
constexpr int HDc = 64;      // head dim
constexpr int NLc = 2;       // layers
constexpr int DFFc = 4096;   // ffn dim
constexpr int LB = Lc * Bc;  // 4096 tokens
constexpr int BHc = Bc * Hc; // 128
constexpr float EPSc = 1e-5f;

__device__ inline unsigned short f2bfu(float f) {
  union { __hip_bfloat16 h; unsigned short u; } cv;
  cv.h = __float2bfloat16(f);
  return cv.u;
}

// ---------------------------------------------------------------------------
// Batched GEMM: C[z][M,N] = A[z][M,K] @ B[z][N,K]^T (+bias) (+=C) (gelu) (bf16 out)
// tile 128x64, BK=64, 256 threads (4 waves). M%128==0, N%64==0, K%64==0 required.
// ---------------------------------------------------------------------------
template <bool ACC, bool GELU, bool OBF>
__global__ __launch_bounds__(256) void gemm_bt(
    int M, int N, int K,
    const bf16* __restrict__ A, int lda, long long sAz,
    const bf16* __restrict__ Bm, int ldb, long long sBz,
    void* __restrict__ Cv, int ldc, long long sCz,
    const float* __restrict__ bias) {
  __shared__ __align__(16) bf16 As[128 * 72];  // +8 pad: 2-way bank aliasing only (free)
  __shared__ __align__(16) bf16 Bs[64 * 72];
  const int tid = threadIdx.x;
  const int w = tid >> 6, lane = tid & 63, quad = lane >> 4, lr = lane & 15;
  const int m0 = blockIdx.x * 128, n0 = blockIdx.y * 64;
  const long long z = blockIdx.z;
  A += z * sAz;
  Bm += z * sBz;
  float* Cf = (float*)Cv;
  bf16* Cb = (bf16*)Cv;

  f32x4 acc[2][4];
#pragma unroll
  for (int i = 0; i < 2; i++)
#pragma unroll
    for (int j = 0; j < 4; j++) acc[i][j] = {0.f, 0.f, 0.f, 0.f};

  for (int k0 = 0; k0 < K; k0 += 64) {
    // stage A 128x64
#pragma unroll
    for (int i = 0; i < 8; i++) {
      int slot = tid + i * 256;  // 2048 slots
      int r = slot >> 4, c4 = (slot & 15) << 2;
      const bf16* srcp = A + (long long)(m0 + r) * lda + k0 + c4;
      *(ushort4*)&As[r * 72 + c4] = *(const ushort4*)srcp;
    }
    // stage B 64x64
#pragma unroll
    for (int i = 0; i < 4; i++) {
      int slot = tid + i * 256;  // 1024 slots
      int r = slot >> 4, c4 = (slot & 15) << 2;
      const bf16* srcp = Bm + (long long)(n0 + r) * ldb + k0 + c4;
      *(ushort4*)&Bs[r * 72 + c4] = *(const ushort4*)srcp;
    }
    __syncthreads();
#pragma unroll
    for (int ks = 0; ks < 64; ks += 32) {
      short8 a[2], b[4];
#pragma unroll
      for (int i = 0; i < 2; i++)
        a[i] = *(const short8*)&As[(w * 32 + i * 16 + lr) * 72 + ks + quad * 8];
#pragma unroll
      for (int j = 0; j < 4; j++)
        b[j] = *(const short8*)&Bs[(j * 16 + lr) * 72 + ks + quad * 8];
#pragma unroll
      for (int i = 0; i < 2; i++)
#pragma unroll
        for (int j = 0; j < 4; j++)
          acc[i][j] = __builtin_amdgcn_mfma_f32_16x16x32_bf16(a[i], b[j], acc[i][j], 0, 0, 0);
    }
    __syncthreads();
  }

  // epilogue: D row = quad*4+r, col = lane&15 (verified gfx950 C/D layout)
#pragma unroll
  for (int i = 0; i < 2; i++) {
#pragma unroll
    for (int j = 0; j < 4; j++) {
      int col = n0 + j * 16 + lr;
      float bv = bias ? bias[col] : 0.f;
#pragma unroll
      for (int r = 0; r < 4; r++) {
        int row = m0 + w * 32 + i * 16 + quad * 4 + r;
        long long off = z * sCz + (long long)row * ldc + col;
        float v = acc[i][j][r] + bv;
        if (ACC) v += Cf[off];
        if (GELU) v = 0.5f * v * (1.f + erff(v * 0.70710678118654752f));
        if (OBF)
          Cb[off] = __float2bfloat16(v);
        else
          Cf[off] = v;
      }
    }
  }
}

// ---------------------------------------------------------------------------
// prep: fp32 -> bf16 conversion (weights)
// ---------------------------------------------------------------------------
__global__ void cvt_bf16(const float* __restrict__ in, bf16* __restrict__ out, long long n) {
  long long i = (long long)blockIdx.x * 256 + threadIdx.x;
  if (i < n) out[i] = __float2bfloat16(in[i]);
}

// x = src (fp32), xb = bf16(src)
__global__ void init_x(const float* __restrict__ src, float* __restrict__ x, bf16* __restrict__ xb) {
  long long i = (long long)blockIdx.x * 256 + threadIdx.x;
  float v = src[i];
  x[i] = v;
  xb[i] = __float2bfloat16(v);
}

// R = pos + typ -> Rb[l,s,d] bf16 and Rt[l,d,s] bf16. grid (L/64 s-tiles, L), 256 thr
__global__ void prep_R(const float* __restrict__ pos, const float* __restrict__ typ,
                       bf16* __restrict__ Rb, bf16* __restrict__ Rt) {
  __shared__ __align__(16) float Ls[64 * 68];
  int l = blockIdx.y, s0 = blockIdx.x * 64;
  int tid = threadIdx.x;
#pragma unroll
  for (int i = 0; i < 4; i++) {
    int slot = tid + i * 256;
    int r = slot >> 4, c = (slot & 15) << 2;  // r = s offset, c = d
    long long off = (((long long)l) * Lc + s0 + r) * HDc + c;
    float4 a = *(const float4*)&pos[off];
    float4 b = *(const float4*)&typ[off];
    float4 s = {a.x + b.x, a.y + b.y, a.z + b.z, a.w + b.w};
    *(float4*)&Ls[r * 68 + c] = s;
    ushort4 o = {f2bfu(s.x), f2bfu(s.y), f2bfu(s.z), f2bfu(s.w)};
    *(ushort4*)&Rb[off] = o;
  }
  __syncthreads();
#pragma unroll
  for (int i = 0; i < 4; i++) {
    int slot = tid + i * 256;
    int d = slot >> 4, s4 = (slot & 15) << 2;
    ushort4 o = {f2bfu(Ls[(s4 + 0) * 68 + d]), f2bfu(Ls[(s4 + 1) * 68 + d]),
                 f2bfu(Ls[(s4 + 2) * 68 + d]), f2bfu(Ls[(s4 + 3) * 68 + d])};
    *(ushort4*)&Rt[(((long long)l) * HDc + d) * Lc + s0 + s4] = o;
  }
}

// P[L*B, 3E] -> q,k bf16 in [B,H,L,HD]; q scaled by HD^-0.5
__global__ void split_qk(const float* __restrict__ P, bf16* __restrict__ q, bf16* __restrict__ k) {
  long long idx = (long long)blockIdx.x * 256 + threadIdx.x;  // over L*B*E
  int col = idx & (Ec - 1);
  long long row = idx >> 10;  // l*B + b
  int l = (int)(row >> 3), b = (int)(row & 7);
  int h = col >> 6, d = col & 63;
  long long dst = (((long long)(b * Hc + h)) * Lc + l) * HDc + d;
  q[dst] = __float2bfloat16(P[row * 3072 + col] * 0.125f);
  k[dst] = __float2bfloat16(P[row * 3072 + Ec + col]);
}

// P v-part -> vt[b,h,d,l] bf16 via LDS transpose. grid (L/64, BH), 256 thr
__global__ void transpose_v(const float* __restrict__ P, bf16* __restrict__ vt) {
  __shared__ __align__(16) float Ls[64 * 68];
  int bh = blockIdx.y, b = bh >> 4, h = bh & 15;
  int l0 = blockIdx.x * 64;
  int tid = threadIdx.x;
#pragma unroll
  for (int i = 0; i < 4; i++) {
    int slot = tid + i * 256;
    int r = slot >> 4, c = (slot & 15) << 2;  // r = l offset, c = d
    float4 v = *(const float4*)&P[((long long)(l0 + r) * Bc + b) * 3072 + 2 * Ec + h * 64 + c];
    *(float4*)&Ls[r * 68 + c] = v;
  }
  __syncthreads();
#pragma unroll
  for (int i = 0; i < 4; i++) {
    int slot = tid + i * 256;
    int d = slot >> 4, s4 = (slot & 15) << 2;
    ushort4 o = {f2bfu(Ls[(s4 + 0) * 68 + d]), f2bfu(Ls[(s4 + 1) * 68 + d]),
                 f2bfu(Ls[(s4 + 2) * 68 + d]), f2bfu(Ls[(s4 + 3) * 68 + d])};
    *(ushort4*)&vt[(((long long)(b * Hc + h)) * HDc + d) * Lc + l0 + s4] = o;
  }
}

// softmax over rows of 512 fp32 -> bf16 probs IN-PLACE (probs row at bf16 offset
// row*1024, overlapping the same fp32 row). One wave per row, 4 rows/block.
// NOTE: no __restrict__ — S and P genuinely alias.
__global__ __launch_bounds__(256) void softmax_rows(const float* S, bf16* P) {
  int w = threadIdx.x >> 6, lane = threadIdx.x & 63;
  long long row = (long long)blockIdx.x * 4 + w;
  const float* sr = S + row * 512;
  float4 v0 = *(const float4*)(sr + lane * 4);
  float4 v1 = *(const float4*)(sr + 256 + lane * 4);
  float mx = fmaxf(fmaxf(fmaxf(v0.x, v0.y), fmaxf(v0.z, v0.w)),
                   fmaxf(fmaxf(v1.x, v1.y), fmaxf(v1.z, v1.w)));
#pragma unroll
  for (int o = 32; o; o >>= 1) mx = fmaxf(mx, __shfl_xor(mx, o, 64));
  float e[8];
  e[0] = __expf(v0.x - mx); e[1] = __expf(v0.y - mx);
  e[2] = __expf(v0.z - mx); e[3] = __expf(v0.w - mx);
  e[4] = __expf(v1.x - mx); e[5] = __expf(v1.y - mx);
  e[6] = __expf(v1.z - mx); e[7] = __expf(v1.w - mx);
  float sum = e[0] + e[1] + e[2] + e[3] + e[4] + e[5] + e[6] + e[7];
#pragma unroll
  for (int o = 32; o; o >>= 1) sum += __shfl_xor(sum, o, 64);
  float inv = 1.f / sum;
  ushort4 o0 = {f2bfu(e[0] * inv), f2bfu(e[1] * inv), f2bfu(e[2] * inv), f2bfu(e[3] * inv)};
  ushort4 o1 = {f2bfu(e[4] * inv), f2bfu(e[5] * inv), f2bfu(e[6] * inv), f2bfu(e[7] * inv)};
  *(ushort4*)(P + row * 1024 + lane * 4) = o0;
  *(ushort4*)(P + row * 1024 + 256 + lane * 4) = o1;
}

// ao2[B,H,L,HD] fp32 -> aob[(l*B+b), h*64+d] bf16
__global__ void merge_ao(const float* __restrict__ ao2, bf16* __restrict__ aob) {
  long long i = (long long)blockIdx.x * 256 + threadIdx.x;  // over B*H*L*HD
  int d = (int)(i & 63);
  long long t = i >> 6;
  int l = (int)(t & (Lc - 1));
  long long bh = t >> 9;
  int b = (int)(bh >> 4), h = (int)(bh & 15);
  aob[((long long)(l * Bc + b)) * Ec + h * 64 + d] = __float2bfloat16(ao2[i]);
}

// x_out = LN(x + c) * g + be; writes fp32 (outF) and bf16 (outB). one row/block
__global__ __launch_bounds__(256) void add_ln(const float* __restrict__ X, const float* __restrict__ Cin,
                                              const float* __restrict__ g, const float* __restrict__ be,
                                              float* __restrict__ outF, bf16* __restrict__ outB) {
  __shared__ float s_sum[4], s_sq[4];
  long long row = blockIdx.x;
  int tid = threadIdx.x;
  float4 xv = *(const float4*)&X[row * Ec + tid * 4];
  float4 cv = *(const float4*)&Cin[row * Ec + tid * 4];
  float v[4] = {xv.x + cv.x, xv.y + cv.y, xv.z + cv.z, xv.w + cv.w};
  float sm = v[0] + v[1] + v[2] + v[3];
  float sq = v[0] * v[0] + v[1] * v[1] + v[2] * v[2] + v[3] * v[3];
#pragma unroll
  for (int o = 32; o; o >>= 1) {
    sm += __shfl_xor(sm, o, 64);
    sq += __shfl_xor(sq, o, 64);
  }
  int w = tid >> 6, lane = tid & 63;
  if (lane == 0) {
    s_sum[w] = sm;
    s_sq[w] = sq;
  }
  __syncthreads();
  sm = s_sum[0] + s_sum[1] + s_sum[2] + s_sum[3];
  sq = s_sq[0] + s_sq[1] + s_sq[2] + s_sq[3];
  float mean = sm * (1.f / Ec);
  float var = sq * (1.f / Ec) - mean * mean;
  float rs = rsqrtf(var + EPSc);
#pragma unroll
  for (int e = 0; e < 4; e++) {
    int n = tid * 4 + e;
    float o = (v[e] - mean) * rs * g[n] + be[n];
    outF[row * Ec + n] = o;
    outB[row * Ec + n] = __float2bfloat16(o);
  }
}

// ---------------------------------------------------------------------------
// Workspace need (bytes), all 256B-aligned blocks:
//   U (P 50MB / scores 134MB+probs-in-place / hb 34MB):  134217728
//   x 16777216, xb 8388608, q 8388608, k 8388608, vt 8388608,
//   ao2c1 16777216, aob 8388608, Rb 33554432, Rt 33554432,
//   wib 12582912, wob 4194304, w1b 16777216, w2b 16777216
// total = 327155712 (312 MiB)
// ---------------------------------------------------------------------------
static constexpr size_t WS_NEED = 327155712;

// Fallback workspace, allocated ONCE at dlopen time (outside kernel_launch and
// outside graph capture). Used only if the harness workspace is too small.
struct GlobalWs {
  void* p = nullptr;
  GlobalWs() {
    if (hipMalloc(&p, WS_NEED) != hipSuccess) p = nullptr;
  }
};
static GlobalWs g_ws;

extern "C" void kernel_launch(void* const* d_in, const int* in_sizes, int n_in,
                              void* d_out, int out_size, void* d_ws, size_t ws_size,
                              hipStream_t stream) {
  const float* src = (const float*)d_in[0];
  const float* pos = (const float*)d_in[1];
  const float* typ = (const float*)d_in[2];
  const float* Wi = (const float*)d_in[3];
  const float* bi = (const float*)d_in[4];
  const float* Wo = (const float*)d_in[5];
  const float* bo = (const float*)d_in[6];
  const float* W1 = (const float*)d_in[7];
  const float* b1 = (const float*)d_in[8];
  const float* W2 = (const float*)d_in[9];
  const float* b2 = (const float*)d_in[10];
  const float* g1 = (const float*)d_in[11];
  const float* be1 = (const float*)d_in[12];
  const float* g2 = (const float*)d_in[13];
  const float* be2 = (const float*)d_in[14];
  float* out = (float*)d_out;
  (void)in_sizes; (void)n_in; (void)out_size;

  // Deterministic workspace choice (same every call): harness ws if big enough,
  // else the static fallback.
  char* wp = (ws_size >= WS_NEED) ? (char*)d_ws : (char*)g_ws.p;
  if (!wp) wp = (char*)d_ws;  // last resort
  auto alloc = [&](size_t bytes) {
    char* r = wp;
    wp += (bytes + 255) & ~(size_t)255;
    return r;
  };

  // Union region: P (QKV out fp32) -> scores fp32 (+ probs bf16 in-place) -> hb bf16
  char* U = alloc((size_t)BHc * Lc * Lc * 4);               // 134 MB
  float* P = (float*)U;
  float* scores = (float*)U;
  bf16* probs = (bf16*)U;                                   // row l at bf16 offset row*1024
  bf16* hb = (bf16*)U;

  float* x = (float*)alloc((size_t)LB * Ec * 4);            // residual fp32
  bf16* xb = (bf16*)alloc((size_t)LB * Ec * 2);             // LN'd bf16 for GEMMs
  bf16* q = (bf16*)alloc((size_t)BHc * Lc * HDc * 2);       // [B,H,L,HD]
  bf16* k = (bf16*)alloc((size_t)BHc * Lc * HDc * 2);
  bf16* vt = (bf16*)alloc((size_t)BHc * HDc * Lc * 2);      // [B,H,HD,L]
  float* ao2 = (float*)alloc((size_t)BHc * Lc * HDc * 4);   // attn out [B,H,L,HD]; aliased as c1
  float* c1 = ao2;                                          // proj / ffn2 out fp32 (disjoint lifetime)
  bf16* aob = (bf16*)alloc((size_t)LB * Ec * 2);            // merged [L*B, E] bf16
  bf16* Rb = (bf16*)alloc((size_t)Lc * Lc * HDc * 2);       // R[l,s,d]
  bf16* Rt = (bf16*)alloc((size_t)Lc * HDc * Lc * 2);       // R^T[l,d,s]
  bf16* wib = (bf16*)alloc((size_t)NLc * 3 * Ec * Ec * 2);
  bf16* wob = (bf16*)alloc((size_t)NLc * Ec * Ec * 2);
  bf16* w1b = (bf16*)alloc((size_t)NLc * DFFc * Ec * 2);
  bf16* w2b = (bf16*)alloc((size_t)NLc * Ec * DFFc * 2);

  // ---- prep
  {
    long long n;
    n = (long long)NLc * 3 * Ec * Ec;
    cvt_bf16<<<(int)((n + 255) / 256), 256, 0, stream>>>(Wi, wib, n);
    n = (long long)NLc * Ec * Ec;
    cvt_bf16<<<(int)((n + 255) / 256), 256, 0, stream>>>(Wo, wob, n);
    n = (long long)NLc * DFFc * Ec;
    cvt_bf16<<<(int)((n + 255) / 256), 256, 0, stream>>>(W1, w1b, n);
    n = (long long)NLc * Ec * DFFc;
    cvt_bf16<<<(int)((n + 255) / 256), 256, 0, stream>>>(W2, w2b, n);
  }
  prep_R<<<dim3(Lc / 64, Lc), 256, 0, stream>>>(pos, typ, Rb, Rt);
  init_x<<<LB * Ec / 256, 256, 0, stream>>>(src, x, xb);

  for (int i = 0; i < NLc; i++) {
    const bf16* Wi_b = wib + (size_t)i * 3 * Ec * Ec;
    const bf16* Wo_b = wob + (size_t)i * Ec * Ec;
    const bf16* W1_b = w1b + (size_t)i * DFFc * Ec;
    const bf16* W2_b = w2b + (size_t)i * Ec * DFFc;

    // QKV projection: P = xb @ Wi^T + bi   [4096, 3072]
    gemm_bt<false, false, false><<<dim3(LB / 128, 3 * Ec / 64, 1), 256, 0, stream>>>(
        LB, 3 * Ec, Ec, xb, Ec, 0, Wi_b, Ec, 0, P, 3 * Ec, 0, bi + (size_t)i * 3 * Ec);
    split_qk<<<LB * Ec / 256, 256, 0, stream>>>(P, q, k);
    transpose_v<<<dim3(Lc / 64, BHc), 256, 0, stream>>>(P, vt);

    // scores = q @ k^T  (batched over bh)   [P dead from here]
    gemm_bt<false, false, false><<<dim3(Lc / 128, Lc / 64, BHc), 256, 0, stream>>>(
        Lc, Lc, HDc, q, HDc, (long long)Lc * HDc, k, HDc, (long long)Lc * HDc,
        scores, Lc, (long long)Lc * Lc, nullptr);
    // scores += q_l @ R_l^T  (batched over l)
    gemm_bt<true, false, false><<<dim3(1, Lc / 64, Lc), 256, 0, stream>>>(
        BHc, Lc, HDc, q, Lc * HDc, (long long)HDc, Rb, HDc, (long long)Lc * HDc,
        scores, Lc * Lc, (long long)Lc, nullptr);

    // softmax, probs bf16 in-place over scores (row stride 1024 bf16 elements)
    softmax_rows<<<BHc * Lc / 4, 256, 0, stream>>>(scores, probs);

    // ao2 = probs @ v  (v^T stored => B^T-form; batched over bh)
    gemm_bt<false, false, false><<<dim3(Lc / 128, 1, BHc), 256, 0, stream>>>(
        Lc, HDc, Lc, probs, 1024, (long long)Lc * 1024, vt, Lc, (long long)HDc * Lc,
        ao2, HDc, (long long)Lc * HDc, nullptr);
    // ao2 += probs_l @ R_l  (R^T stored => B^T-form; batched over l)
    gemm_bt<true, false, false><<<dim3(1, 1, Lc), 256, 0, stream>>>(
        BHc, HDc, Lc, probs, Lc * 1024, (long long)1024, Rt, Lc, (long long)HDc * Lc,
        ao2, Lc * HDc, (long long)HDc, nullptr);

    merge_ao<<<BHc * Lc * HDc / 256, 256, 0, stream>>>(ao2, aob);

    // output projection: c1 = aob @ Wo^T + bo   [ao2 dead; c1 aliases it]
    gemm_bt<false, false, false><<<dim3(LB / 128, Ec / 64, 1), 256, 0, stream>>>(
        LB, Ec, Ec, aob, Ec, 0, Wo_b, Ec, 0, c1, Ec, 0, bo + (size_t)i * Ec);
    add_ln<<<LB, 256, 0, stream>>>(x, c1, g1 + (size_t)i * Ec, be1 + (size_t)i * Ec, x, xb);

    // ffn1: hb = gelu(xb @ W1^T + b1)  bf16 out   [probs dead; hb aliases U]
    gemm_bt<false, true, true><<<dim3(LB / 128, DFFc / 64, 1), 256, 0, stream>>>(
        LB, DFFc, Ec, xb, Ec, 0, W1_b, Ec, 0, hb, DFFc, 0, b1 + (size_t)i * DFFc);
    // ffn2: c1 = hb @ W2^T + b2
    gemm_bt<false, false, false><<<dim3(LB / 128, Ec / 64, 1), 256, 0, stream>>>(
        LB, Ec, DFFc, hb, DFFc, 0, W2_b, DFFc, 0, c1, Ec, 0, b2 + (size_t)i * Ec);

    float* outF = (i == NLc - 1) ? out : x;
    add_ln<<<LB, 256, 0, stream>>>(x, c1, g2 + (size_t)i * Ec, be2 + (size_t)i * Ec, outF, xb);
  }
}